// Round 2
// baseline (212.183 us; speedup 1.0000x reference)
//
#include <hip/hip_runtime.h>
#include <hip/hip_bf16.h>

// Problem constants (fixed by the reference setup)
#define BGR  128          // graphs
#define NPG  111          // nodes per graph
#define HDIM 32           // hidden
#define EPG  (NPG*(NPG-1))// 12210 directed edges per graph
#define NTOT (BGR*NPG)    // 14208 nodes
#define PADW 112          // padded row length for eatt rows ([d][s], s in [0,111))

// ---------------------------------------------------------------------------
// Kernel 1: per-layer edge-attention scalar, transposed to [g][d][s] layout.
// eatt[s->d] = ea.x*c0 + ea.y*c1 with (c0,c1) = We @ ae.
// Diagonal (self-loop, fill='mean') = rowsum/110 (linear in ea).
// grid = 3*BGR blocks of 256.
__global__ void eatt_kernel(const float* __restrict__ ea,
                            const float* __restrict__ We0, const float* __restrict__ ae0,
                            const float* __restrict__ We1, const float* __restrict__ ae1,
                            const float* __restrict__ We2, const float* __restrict__ ae2,
                            float* __restrict__ eatt) {
    int l = blockIdx.x / BGR;
    int g = blockIdx.x % BGR;
    const float* We = (l == 0) ? We0 : ((l == 1) ? We1 : We2);
    const float* ae = (l == 0) ? ae0 : ((l == 1) ? ae1 : ae2);

    __shared__ float tile[NPG * PADW];
    __shared__ float cvec[2];
    int t = threadIdx.x;

    // c = We @ ae  (We is [2][32] row-major)
    if (t < 64) {
        int r = t >> 5, k = t & 31;
        float p = We[r * 32 + k] * ae[k];
        for (int off = 1; off < 32; off <<= 1) p += __shfl_xor(p, off);
        if (k == 0) cvec[r] = p;
    }
    __syncthreads();
    float c0 = cvec[0], c1 = cvec[1];

    const float* eg = ea + (size_t)g * EPG * 2;
    for (int e = t; e < EPG; e += 256) {
        float2 v = ((const float2*)eg)[e];
        int s = e / 110;
        int j = e - s * 110;
        int d = j + (j >= s ? 1 : 0);
        tile[d * PADW + s] = v.x * c0 + v.y * c1;
    }
    __syncthreads();

    // diagonal: mean of incoming (one wave per row, conflict-free)
    int wave = t >> 6, lane = t & 63;
    for (int d = wave; d < NPG; d += 4) {
        float a = (lane != d) ? tile[d * PADW + lane] : 0.f;
        int s2 = lane + 64;
        float b = (s2 < NPG && s2 != d) ? tile[d * PADW + s2] : 0.f;
        float p = a + b;
        for (int off = 1; off < 64; off <<= 1) p += __shfl_xor(p, off);
        if (lane == 0) tile[d * PADW + d] = p * (1.f / 110.f);
    }
    __syncthreads();

    float* out = eatt + (size_t)(l * BGR + g) * NPG * PADW;
    for (int i = t; i < NPG * PADW; i += 256) out[i] = tile[i];
}

// ---------------------------------------------------------------------------
// Kernel 2: projection h = xin @ W, plus as_v = h.a_s, ad_v = h.a_d.
// din = 1 (layer 0) or 32; do_relu applies relu to xin (layer-2 input).
// grid = NTOT/8 blocks of 256 (8 nodes x 32 channels per block).
__global__ void proj_kernel(const float* __restrict__ xin, int din, int do_relu,
                            const float* __restrict__ W,
                            const float* __restrict__ as_w, const float* __restrict__ ad_w,
                            float* __restrict__ h, float* __restrict__ asv,
                            float* __restrict__ adv) {
    __shared__ float Ws[32 * 32];
    __shared__ float xs[8 * 32];
    __shared__ float asw[32], adw[32];
    int t = threadIdx.x;
    // FIX (round 1): din*32 can be 1024 > blockDim; must stride-loop.
    for (int i = t; i < din * 32; i += 256) Ws[i] = W[i];
    if (t < 32) { asw[t] = as_w[t]; adw[t] = ad_w[t]; }
    int i0 = blockIdx.x * 8;
    if (din == 32) {
        xs[t] = xin[(size_t)i0 * 32 + t];
    } else if (t < 8) {
        xs[t] = xin[i0 + t];
    }
    __syncthreads();

    int il = t >> 5, c = t & 31;
    float hv;
    if (din == 1) {
        hv = xs[il] * Ws[c];
    } else {
        float acc = 0.f;
        #pragma unroll
        for (int k = 0; k < 32; k++) {
            float xv = xs[il * 32 + k];
            if (do_relu) xv = fmaxf(xv, 0.f);
            acc += xv * Ws[k * 32 + c];
        }
        hv = acc;
    }
    int i = i0 + il;
    h[(size_t)i * 32 + c] = hv;
    float ps = hv * asw[c], pd = hv * adw[c];
    for (int off = 1; off < 32; off <<= 1) {
        ps += __shfl_xor(ps, off);
        pd += __shfl_xor(pd, off);
    }
    if (c == 0) { asv[i] = ps; adv[i] = pd; }
}

// ---------------------------------------------------------------------------
// Kernel 3: dense per-graph GAT attention + aggregation.
// grid = BGR*8 blocks of 256; block = (graph g, dst slice of 14), wave = 1 dst.
#define DPB 14
__global__ void gat_kernel(const float* __restrict__ h_in,
                           const float* __restrict__ asv, const float* __restrict__ adv,
                           const float* __restrict__ eatt_l,  // [BGR][NPG][PADW]
                           const float* __restrict__ bias,
                           float* __restrict__ h_out) {
    int g = blockIdx.x >> 3;
    int part = blockIdx.x & 7;

    __shared__ float hs[NPG * 32];
    __shared__ float ass[NPG], ads[NPG];
    __shared__ float coef[4][PADW];
    __shared__ float bs[32];

    int t = threadIdx.x;
    const float* hg = h_in + (size_t)g * NPG * 32;
    for (int i = t; i < NPG * 32; i += 256) hs[i] = hg[i];
    if (t < NPG) { ass[t] = asv[g * NPG + t]; ads[t] = adv[g * NPG + t]; }
    if (t < 32) bs[t] = bias[t];
    __syncthreads();

    int wave = t >> 6, lane = t & 63;
    const float* er = eatt_l + (size_t)g * NPG * PADW;

    for (int it = 0; it < 4; it++) {
        int dl = wave * 4 + it;            // 0..15
        int d = part * DPB + dl;
        bool active = (dl < DPB) && (d < NPG);

        // ---- scores (lane covers sources lane and lane+64) ----
        float s1 = -1e30f, s2 = -1e30f;
        if (active) {
            float add = ads[d];
            {
                float a = ass[lane] + add + er[(size_t)d * PADW + lane];
                s1 = (a > 0.f) ? a : 0.2f * a;      // lane < 111 always
            }
            int sB = lane + 64;
            if (sB < NPG) {
                float a = ass[sB] + add + er[(size_t)d * PADW + sB];
                s2 = (a > 0.f) ? a : 0.2f * a;
            }
        }
        float m = fmaxf(s1, s2);
        for (int off = 1; off < 64; off <<= 1) m = fmaxf(m, __shfl_xor(m, off));
        float e1 = (s1 > -1e29f) ? __expf(s1 - m) : 0.f;
        float e2 = (s2 > -1e29f) ? __expf(s2 - m) : 0.f;
        float sum = e1 + e2;
        for (int off = 1; off < 64; off <<= 1) sum += __shfl_xor(sum, off);
        float inv = 1.f / sum;
        if (active) {
            coef[wave][lane] = e1 * inv;
            if (lane + 64 < NPG) coef[wave][lane + 64] = e2 * inv;
        }
        __syncthreads();   // uniform; enforces coef write->read ordering

        // ---- aggregation: out[d][c] = sum_s coef[s] * h[s][c] ----
        float acc = 0.f;
        if (active) {
            int c = lane & 31;
            int sbeg = (lane < 32) ? 0 : 56;
            int send = (lane < 32) ? 56 : NPG;
            const float* cf = coef[wave];
            for (int s = sbeg; s < send; s++)
                acc += cf[s] * hs[s * 32 + c];
        }
        acc += __shfl_xor(acc, 32);
        if (active && lane < 32) {
            h_out[((size_t)g * NPG + d) * 32 + lane] = acc + bs[lane];
        }
        __syncthreads();
    }
}

// ---------------------------------------------------------------------------
// Kernel 4: global_add_pool + final linear + relu. grid = BGR blocks of 256.
__global__ void pool_kernel(const float* __restrict__ h2,
                            const float* __restrict__ linW,
                            const float* __restrict__ linb,
                            float* __restrict__ out) {
    int g = blockIdx.x;
    int t = threadIdx.x;
    int c = t & 31, r = t >> 5;   // 8 row-groups
    const float* hg = h2 + (size_t)g * NPG * 32;
    float acc = 0.f;
    for (int i = r; i < NPG; i += 8) acc += hg[i * 32 + c];
    __shared__ float red[8][33];
    red[r][c] = acc;
    __syncthreads();
    if (t < 32) {
        float p = 0.f;
        #pragma unroll
        for (int rr = 0; rr < 8; rr++) p += red[rr][t];
        p *= linW[t];
        for (int off = 1; off < 32; off <<= 1) p += __shfl_xor(p, off);
        if (t == 0) out[g] = fmaxf(p + linb[0], 0.f);
    }
}

// ---------------------------------------------------------------------------
extern "C" void kernel_launch(void* const* d_in, const int* in_sizes, int n_in,
                              void* d_out, int out_size, void* d_ws, size_t ws_size,
                              hipStream_t stream) {
    // input order: x, edge_index, edge_attr, {W,as,ad,We,ae,b} x3, lin_W, lin_b
    const float* x    = (const float*)d_in[0];
    const float* ea   = (const float*)d_in[2];
    const float* W[3]  = {(const float*)d_in[3],  (const float*)d_in[9],  (const float*)d_in[15]};
    const float* as_[3]= {(const float*)d_in[4],  (const float*)d_in[10], (const float*)d_in[16]};
    const float* ad_[3]= {(const float*)d_in[5],  (const float*)d_in[11], (const float*)d_in[17]};
    const float* We[3] = {(const float*)d_in[6],  (const float*)d_in[12], (const float*)d_in[18]};
    const float* ae[3] = {(const float*)d_in[7],  (const float*)d_in[13], (const float*)d_in[19]};
    const float* b[3]  = {(const float*)d_in[8],  (const float*)d_in[14], (const float*)d_in[20]};
    const float* linW  = (const float*)d_in[21];
    const float* linb  = (const float*)d_in[22];
    float* out = (float*)d_out;

    float* ws    = (float*)d_ws;
    float* eatt  = ws;                                      // 3*BGR*NPG*PADW
    float* hproj = eatt  + (size_t)3 * BGR * NPG * PADW;    // NTOT*32
    float* hgat  = hproj + (size_t)NTOT * 32;               // NTOT*32
    float* asv   = hgat  + (size_t)NTOT * 32;               // NTOT
    float* adv   = asv   + (size_t)NTOT;                    // NTOT

    eatt_kernel<<<3 * BGR, 256, 0, stream>>>(ea, We[0], ae[0], We[1], ae[1],
                                             We[2], ae[2], eatt);

    const float* cur = x;
    for (int l = 0; l < 3; l++) {
        proj_kernel<<<NTOT / 8, 256, 0, stream>>>(cur, (l == 0) ? 1 : 32,
                                                  (l == 2) ? 1 : 0,
                                                  W[l], as_[l], ad_[l],
                                                  hproj, asv, adv);
        gat_kernel<<<BGR * 8, 256, 0, stream>>>(hproj, asv, adv,
                                                eatt + (size_t)l * BGR * NPG * PADW,
                                                b[l], hgat);
        cur = hgat;
    }

    pool_kernel<<<BGR, 256, 0, stream>>>(hgat, linW, linb, out);
}

// Round 3
// 182.323 us; speedup vs baseline: 1.1638x; 1.1638x over previous
//
#include <hip/hip_runtime.h>
#include <hip/hip_bf16.h>

// Problem constants (fixed by the reference setup)
#define BGR  128          // graphs
#define NPG  111          // nodes per graph
#define HDIM 32           // hidden
#define EPG  (NPG*(NPG-1))// 12210 directed edges per graph
#define NTOT (BGR*NPG)    // 14208 nodes
#define PADW 112          // global row length for eatt rows ([d][s])
#define PADT 113          // LDS-internal row pad (stride%32=17, coprime -> conflict-free)

// ---------------------------------------------------------------------------
// Kernel 1: per-layer edge-attention scalar, transposed to [g][d][s] layout.
// eatt[s->d] = ea.x*c0 + ea.y*c1 with (c0,c1) = We @ ae.
// Diagonal (self-loop, fill='mean') = rowsum/110 (linear in ea).
// grid = 3*BGR blocks of 256.
__global__ void eatt_kernel(const float* __restrict__ ea,
                            const float* __restrict__ We0, const float* __restrict__ ae0,
                            const float* __restrict__ We1, const float* __restrict__ ae1,
                            const float* __restrict__ We2, const float* __restrict__ ae2,
                            float* __restrict__ eatt) {
    int l = blockIdx.x / BGR;
    int g = blockIdx.x % BGR;
    const float* We = (l == 0) ? We0 : ((l == 1) ? We1 : We2);
    const float* ae = (l == 0) ? ae0 : ((l == 1) ? ae1 : ae2);

    __shared__ float tile[NPG * PADT];   // 49.0 KB, stride 113 kills bank conflicts
    __shared__ float cvec[2];
    int t = threadIdx.x;

    // c = We @ ae  (We is [2][32] row-major)
    if (t < 64) {
        int r = t >> 5, k = t & 31;
        float p = We[r * 32 + k] * ae[k];
        for (int off = 1; off < 32; off <<= 1) p += __shfl_xor(p, off);
        if (k == 0) cvec[r] = p;
    }
    __syncthreads();
    float c0 = cvec[0], c1 = cvec[1];

    const float* eg = ea + (size_t)g * EPG * 2;
    for (int e = t; e < EPG; e += 256) {
        float2 v = ((const float2*)eg)[e];
        int s = e / 110;
        int j = e - s * 110;
        int d = j + (j >= s ? 1 : 0);
        tile[d * PADT + s] = v.x * c0 + v.y * c1;   // bank step 17: conflict-free
    }
    __syncthreads();

    // diagonal: mean of incoming (one wave per row, conflict-free)
    int wave = t >> 6, lane = t & 63;
    for (int d = wave; d < NPG; d += 4) {
        float a = (lane != d) ? tile[d * PADT + lane] : 0.f;
        int s2 = lane + 64;
        float b = (s2 < NPG && s2 != d) ? tile[d * PADT + s2] : 0.f;
        float p = a + b;
        for (int off = 1; off < 64; off <<= 1) p += __shfl_xor(p, off);
        if (lane == 0) tile[d * PADT + d] = p * (1.f / 110.f);
    }
    __syncthreads();

    // write out in [d][PADW=112] layout (read side of gat wants contiguous rows)
    float* out = eatt + (size_t)(l * BGR + g) * NPG * PADW;
    for (int i = t; i < NPG * PADW; i += 256) {
        int d = i / PADW, s = i - d * PADW;
        out[i] = tile[d * PADT + s];
    }
}

// ---------------------------------------------------------------------------
// Kernel 2: projection h = xin @ W, plus as_v = h.a_s, ad_v = h.a_d.
// din = 1 (layer 0) or 32; do_relu applies relu to xin (layer-2 input).
// grid = NTOT/8 blocks of 256 (8 nodes x 32 channels per block).
__global__ void proj_kernel(const float* __restrict__ xin, int din, int do_relu,
                            const float* __restrict__ W,
                            const float* __restrict__ as_w, const float* __restrict__ ad_w,
                            float* __restrict__ h, float* __restrict__ asv,
                            float* __restrict__ adv) {
    __shared__ float Ws[32 * 32];
    __shared__ float xs[8 * 32];
    __shared__ float asw[32], adw[32];
    int t = threadIdx.x;
    for (int i = t; i < din * 32; i += 256) Ws[i] = W[i];
    if (t < 32) { asw[t] = as_w[t]; adw[t] = ad_w[t]; }
    int i0 = blockIdx.x * 8;
    if (din == 32) {
        xs[t] = xin[(size_t)i0 * 32 + t];
    } else if (t < 8) {
        xs[t] = xin[i0 + t];
    }
    __syncthreads();

    int il = t >> 5, c = t & 31;
    float hv;
    if (din == 1) {
        hv = xs[il] * Ws[c];
    } else {
        float acc = 0.f;
        #pragma unroll
        for (int k = 0; k < 32; k++) {
            float xv = xs[il * 32 + k];
            if (do_relu) xv = fmaxf(xv, 0.f);
            acc += xv * Ws[k * 32 + c];
        }
        hv = acc;
    }
    int i = i0 + il;
    h[(size_t)i * 32 + c] = hv;
    float ps = hv * asw[c], pd = hv * adw[c];
    for (int off = 1; off < 32; off <<= 1) {
        ps += __shfl_xor(ps, off);
        pd += __shfl_xor(pd, off);
    }
    if (c == 0) { asv[i] = ps; adv[i] = pd; }
}

// ---------------------------------------------------------------------------
// Kernel 3: dense per-graph GAT attention + aggregation.
// grid = BGR*8 blocks of 256; block = (graph g, dst slice of 14).
// v2: eatt rows staged in LDS, ONE barrier per block, per-wave coef (no
// cross-wave sync needed), 4 dsts per wave in one aggregation loop so each
// hs LDS read feeds 4 FMAs.
#define DPB 14
__global__ __launch_bounds__(256) void
gat_kernel(const float* __restrict__ h_in,
           const float* __restrict__ asv, const float* __restrict__ adv,
           const float* __restrict__ eatt_l,  // [BGR][NPG][PADW]
           const float* __restrict__ bias,
           float* __restrict__ h_out) {
    int g = blockIdx.x >> 3;
    int part = blockIdx.x & 7;

    __shared__ float hs[112 * 32];        // row 111 zeroed (padding row)
    __shared__ float ers[DPB * PADW];     // this block's eatt rows
    __shared__ float ass[NPG];
    __shared__ float adsb[DPB];
    __shared__ float coef[4][4][PADW];    // [wave][p][s]; strictly per-wave
    __shared__ float bs[32];

    int t = threadIdx.x;
    // ---- staging (float4) ----
    const float4* hg4 = (const float4*)(h_in + (size_t)g * NPG * 32);
    for (int i = t; i < NPG * 8; i += 256) ((float4*)hs)[i] = hg4[i];
    if (t < 32) hs[111 * 32 + t] = 0.f;   // zero pad row (s=111)
    int nrow = (part == 7) ? (NPG - 7 * DPB) : DPB;           // 13 or 14
    const float4* er4 = (const float4*)(eatt_l + ((size_t)g * NPG + part * DPB) * PADW);
    for (int i = t; i < nrow * (PADW / 4); i += 256) ((float4*)ers)[i] = er4[i];
    if (t < NPG) ass[t] = asv[g * NPG + t];
    if (t < DPB) {
        int d = part * DPB + t;
        adsb[t] = (d < NPG) ? adv[g * NPG + d] : 0.f;
    }
    if (t < 32) bs[t] = bias[t];
    __syncthreads();   // the only block-wide barrier

    int wave = t >> 6, lane = t & 63;
    bool actp[4];
    // ---- softmax for this wave's 4 dsts -> coef[wave][p][*] ----
    for (int p = 0; p < 4; p++) {
        int dl = wave * 4 + p;
        int d = part * DPB + dl;
        bool act = (dl < DPB) && (d < NPG);
        actp[p] = act;
        float s1 = -1e30f, s2 = -1e30f;
        if (act) {
            float add = adsb[dl];
            const float* er = &ers[dl * PADW];
            float a1 = ass[lane] + add + er[lane];
            s1 = (a1 > 0.f) ? a1 : 0.2f * a1;
            int sB = lane + 64;
            if (sB < NPG) {
                float a2 = ass[sB] + add + er[sB];
                s2 = (a2 > 0.f) ? a2 : 0.2f * a2;
            }
        }
        float m = fmaxf(s1, s2);
        for (int off = 1; off < 64; off <<= 1) m = fmaxf(m, __shfl_xor(m, off));
        float e1 = (s1 > -1e29f) ? __expf(s1 - m) : 0.f;
        float e2 = (s2 > -1e29f) ? __expf(s2 - m) : 0.f;
        float sum = e1 + e2;
        for (int off = 1; off < 64; off <<= 1) sum += __shfl_xor(sum, off);
        float inv = (sum > 0.f) ? (1.f / sum) : 0.f;
        coef[wave][p][lane] = e1 * inv;
        float c2v = (lane + 64 < NPG) ? e2 * inv : 0.f;
        if (lane + 64 < PADW) coef[wave][p][lane + 64] = c2v;  // s=111 -> 0
    }
    // same-wave LDS write->read: in-order LDS pipe + compiler alias ordering;
    // no __syncthreads needed (coef is per-wave).

    // ---- aggregation: 4 dsts share each hs read ----
    int c = lane & 31;
    int sbase = (lane >> 5) * 56;       // half 0: s=0..55, half 1: s=56..111
    float acc0 = 0.f, acc1 = 0.f, acc2 = 0.f, acc3 = 0.f;
    const float* cw0 = coef[wave][0];
    const float* cw1 = coef[wave][1];
    const float* cw2 = coef[wave][2];
    const float* cw3 = coef[wave][3];
    #pragma unroll 8
    for (int j = 0; j < 56; j++) {
        int s = sbase + j;              // max 111: hs row 111 = 0, coef[111] = 0
        float hval = hs[s * 32 + c];
        acc0 += cw0[s] * hval;
        acc1 += cw1[s] * hval;
        acc2 += cw2[s] * hval;
        acc3 += cw3[s] * hval;
    }
    acc0 += __shfl_xor(acc0, 32);
    acc1 += __shfl_xor(acc1, 32);
    acc2 += __shfl_xor(acc2, 32);
    acc3 += __shfl_xor(acc3, 32);
    if (lane < 32) {
        float bv = bs[lane];
        int dbase = (size_t)g * NPG + part * DPB + wave * 4;
        if (actp[0]) h_out[((size_t)dbase + 0) * 32 + lane] = acc0 + bv;
        if (actp[1]) h_out[((size_t)dbase + 1) * 32 + lane] = acc1 + bv;
        if (actp[2]) h_out[((size_t)dbase + 2) * 32 + lane] = acc2 + bv;
        if (actp[3]) h_out[((size_t)dbase + 3) * 32 + lane] = acc3 + bv;
    }
}

// ---------------------------------------------------------------------------
// Kernel 4: global_add_pool + final linear + relu. grid = BGR blocks of 256.
__global__ void pool_kernel(const float* __restrict__ h2,
                            const float* __restrict__ linW,
                            const float* __restrict__ linb,
                            float* __restrict__ out) {
    int g = blockIdx.x;
    int t = threadIdx.x;
    int c = t & 31, r = t >> 5;   // 8 row-groups
    const float* hg = h2 + (size_t)g * NPG * 32;
    float acc = 0.f;
    for (int i = r; i < NPG; i += 8) acc += hg[i * 32 + c];
    __shared__ float red[8][33];
    red[r][c] = acc;
    __syncthreads();
    if (t < 32) {
        float p = 0.f;
        #pragma unroll
        for (int rr = 0; rr < 8; rr++) p += red[rr][t];
        p *= linW[t];
        for (int off = 1; off < 32; off <<= 1) p += __shfl_xor(p, off);
        if (t == 0) out[g] = fmaxf(p + linb[0], 0.f);
    }
}

// ---------------------------------------------------------------------------
extern "C" void kernel_launch(void* const* d_in, const int* in_sizes, int n_in,
                              void* d_out, int out_size, void* d_ws, size_t ws_size,
                              hipStream_t stream) {
    // input order: x, edge_index, edge_attr, {W,as,ad,We,ae,b} x3, lin_W, lin_b
    const float* x    = (const float*)d_in[0];
    const float* ea   = (const float*)d_in[2];
    const float* W[3]  = {(const float*)d_in[3],  (const float*)d_in[9],  (const float*)d_in[15]};
    const float* as_[3]= {(const float*)d_in[4],  (const float*)d_in[10], (const float*)d_in[16]};
    const float* ad_[3]= {(const float*)d_in[5],  (const float*)d_in[11], (const float*)d_in[17]};
    const float* We[3] = {(const float*)d_in[6],  (const float*)d_in[12], (const float*)d_in[18]};
    const float* ae[3] = {(const float*)d_in[7],  (const float*)d_in[13], (const float*)d_in[19]};
    const float* b[3]  = {(const float*)d_in[8],  (const float*)d_in[14], (const float*)d_in[20]};
    const float* linW  = (const float*)d_in[21];
    const float* linb  = (const float*)d_in[22];
    float* out = (float*)d_out;

    float* ws    = (float*)d_ws;
    float* eatt  = ws;                                      // 3*BGR*NPG*PADW
    float* hproj = eatt  + (size_t)3 * BGR * NPG * PADW;    // NTOT*32
    float* hgat  = hproj + (size_t)NTOT * 32;               // NTOT*32
    float* asv   = hgat  + (size_t)NTOT * 32;               // NTOT
    float* adv   = asv   + (size_t)NTOT;                    // NTOT

    eatt_kernel<<<3 * BGR, 256, 0, stream>>>(ea, We[0], ae[0], We[1], ae[1],
                                             We[2], ae[2], eatt);

    const float* cur = x;
    for (int l = 0; l < 3; l++) {
        proj_kernel<<<NTOT / 8, 256, 0, stream>>>(cur, (l == 0) ? 1 : 32,
                                                  (l == 2) ? 1 : 0,
                                                  W[l], as_[l], ad_[l],
                                                  hproj, asv, adv);
        gat_kernel<<<BGR * 8, 256, 0, stream>>>(hproj, asv, adv,
                                                eatt + (size_t)l * BGR * NPG * PADW,
                                                b[l], hgat);
        cur = hgat;
    }

    pool_kernel<<<BGR, 256, 0, stream>>>(hgat, linW, linb, out);
}